// Round 1
// baseline (4595.424 us; speedup 1.0000x reference)
//
#include <hip/hip_runtime.h>
#include <math.h>

#define BB 2
#define LL 2048
#define EE 2048
#define HH 16
#define HD 128
#define N3E (3*EE)   // 6144

// ---------------- GEMM: C = A @ W + bias ----------------
// A [M,K] row-major, W [K,N] row-major, C [M,N]. tile 64x64, BK=16,
// 256 threads, 4x4 per thread. M,N,K must be multiples of 64/64/16.
__global__ __launch_bounds__(256) void gemm_bias(const float* __restrict__ A,
                                                 const float* __restrict__ W,
                                                 const float* __restrict__ bias,
                                                 float* __restrict__ C,
                                                 int M, int N, int K) {
    __shared__ float As[16][68];   // [k][m], padded to 68 (16B-aligned rows, conflict-spread)
    __shared__ float Bs[16][64];   // [k][n]
    const int t  = threadIdx.x;
    const int tx = t & 15, ty = t >> 4;
    const int n0 = blockIdx.x * 64;
    const int m0 = blockIdx.y * 64;
    float acc[4][4] = {};
    for (int k0 = 0; k0 < K; k0 += 16) {
        #pragma unroll
        for (int i = 0; i < 4; ++i) {       // A tile 64x16 -> As[k][m]
            int ii = t + i * 256;
            int m = ii >> 4, k = ii & 15;   // consecutive t -> consecutive k (coalesced 64B)
            As[k][m] = A[(size_t)(m0 + m) * K + k0 + k];
        }
        #pragma unroll
        for (int i = 0; i < 4; ++i) {       // W tile 16x64 -> Bs[k][n]
            int ii = t + i * 256;
            int k = ii >> 6, n = ii & 63;   // consecutive t -> consecutive n (coalesced 256B)
            Bs[k][n] = W[(size_t)(k0 + k) * N + n0 + n];
        }
        __syncthreads();
        #pragma unroll
        for (int k = 0; k < 16; ++k) {
            float4 a4 = *(const float4*)&As[k][ty * 4];
            float4 b4 = *(const float4*)&Bs[k][tx * 4];
            float av[4] = {a4.x, a4.y, a4.z, a4.w};
            float bv[4] = {b4.x, b4.y, b4.z, b4.w};
            #pragma unroll
            for (int i = 0; i < 4; ++i)
                #pragma unroll
                for (int j = 0; j < 4; ++j)
                    acc[i][j] += av[i] * bv[j];
        }
        __syncthreads();
    }
    #pragma unroll
    for (int i = 0; i < 4; ++i) {
        int m = m0 + ty * 4 + i;
        #pragma unroll
        for (int j = 0; j < 4; ++j) {
            int n = n0 + tx * 4 + j;
            C[(size_t)m * N + n] = acc[i][j] + bias[n];
        }
    }
}

// ---------------- RoPE in-place on q,k slices of qkv [B,L,3E] ----------------
// one thread per (b,l,h,j) with j in [0,64): rotates pairs (j, j+64)
__global__ __launch_bounds__(256) void rope_kernel(float* __restrict__ qkv,
                                                   const int* __restrict__ pos_ids) {
    int idx = blockIdx.x * 256 + threadIdx.x;   // B*L*H*64 total
    int j  = idx & 63;
    int h  = (idx >> 6) & 15;
    int bl = idx >> 10;                          // b*L + l
    float pos = (float)pos_ids[bl];
    float inv = powf(10000.0f, -(float)(2 * j) / 128.0f);
    float ang = pos * inv;
    float c = cosf(ang), s = sinf(ang);
    size_t base = (size_t)bl * N3E + h * HD;
    float x1 = qkv[base + j], x2 = qkv[base + j + 64];
    qkv[base + j]      = x1 * c - x2 * s;
    qkv[base + j + 64] = x2 * c + x1 * s;
    base += EE;   // k slice
    x1 = qkv[base + j]; x2 = qkv[base + j + 64];
    qkv[base + j]      = x1 * c - x2 * s;
    qkv[base + j + 64] = x2 * c + x1 * s;
}

// ---------------- Flash attention (fp32, online softmax) ----------------
// block: 256 threads, 32 q-rows for one (b,h); loops 32-key tiles.
#define BQ 32
#define BKV 32
#define QSTR 132   // padded row stride (multiple of 4 -> float4-aligned rows)

__global__ __launch_bounds__(256) void flash_attn(const float* __restrict__ qkv,
                                                  float* __restrict__ y) {
    __shared__ float Qs[BQ][QSTR];
    __shared__ float Ks[BKV][QSTR];
    __shared__ float Vs[BKV][QSTR];
    __shared__ float Sm[BQ][33];
    __shared__ float mrow[BQ], lrow[BQ], arow[BQ];
    const int t  = threadIdx.x;
    const int q0 = blockIdx.x * BQ;
    const int bh = blockIdx.y;
    const int b  = bh >> 4, h = bh & 15;
    const float scale = 0.08838834764831845f;    // 1/sqrt(128)
    const float* qbase = qkv + (size_t)b * LL * N3E + h * HD;
    const float* kbase = qbase + EE;
    const float* vbase = qbase + 2 * EE;

    for (int ii = t; ii < BQ * HD; ii += 256) {
        int r = ii >> 7, c = ii & 127;
        Qs[r][c] = qbase[(size_t)(q0 + r) * N3E + c] * scale;
    }
    if (t < BQ) { mrow[t] = -INFINITY; lrow[t] = 0.f; }

    const int r  = t >> 3;          // 0..31  (O-frag row)
    const int d0 = (t & 7) * 16;    // 0..112 (O-frag col start)
    const int c0 = (t & 7) * 4;     // S-frag col start
    float o[16];
    #pragma unroll
    for (int i = 0; i < 16; ++i) o[i] = 0.f;

    for (int kt = 0; kt < LL; kt += BKV) {
        __syncthreads();            // protect Ks/Vs from previous PV reads
        for (int ii = t; ii < BKV * HD; ii += 256) {
            int rr = ii >> 7, c = ii & 127;
            Ks[rr][c] = kbase[(size_t)(kt + rr) * N3E + c];
            Vs[rr][c] = vbase[(size_t)(kt + rr) * N3E + c];
        }
        __syncthreads();
        // ---- S = Qs @ Ks^T : thread computes S[r][c0..c0+3]
        {
            float a0 = 0.f, a1 = 0.f, a2 = 0.f, a3 = 0.f;
            const float4* q4  = (const float4*)&Qs[r][0];
            const float4* k40 = (const float4*)&Ks[c0 + 0][0];
            const float4* k41 = (const float4*)&Ks[c0 + 1][0];
            const float4* k42 = (const float4*)&Ks[c0 + 2][0];
            const float4* k43 = (const float4*)&Ks[c0 + 3][0];
            #pragma unroll
            for (int kk = 0; kk < HD / 4; ++kk) {
                float4 qv = q4[kk];
                float4 kv;
                kv = k40[kk]; a0 += qv.x*kv.x + qv.y*kv.y + qv.z*kv.z + qv.w*kv.w;
                kv = k41[kk]; a1 += qv.x*kv.x + qv.y*kv.y + qv.z*kv.z + qv.w*kv.w;
                kv = k42[kk]; a2 += qv.x*kv.x + qv.y*kv.y + qv.z*kv.z + qv.w*kv.w;
                kv = k43[kk]; a3 += qv.x*kv.x + qv.y*kv.y + qv.z*kv.z + qv.w*kv.w;
            }
            Sm[r][c0 + 0] = a0; Sm[r][c0 + 1] = a1;
            Sm[r][c0 + 2] = a2; Sm[r][c0 + 3] = a3;
        }
        __syncthreads();
        // ---- phase A: row max + alpha (32 threads)
        if (t < BQ) {
            float mx = mrow[t];
            #pragma unroll
            for (int c = 0; c < BKV; ++c) mx = fmaxf(mx, Sm[t][c]);
            arow[t] = expf(mrow[t] - mx);   // -inf old m -> alpha 0
            mrow[t] = mx;
        }
        __syncthreads();
        // ---- phase B: exponentiate in place (all 256 threads, 4 elems each)
        {
            float mx = mrow[r];
            #pragma unroll
            for (int j = 0; j < 4; ++j)
                Sm[r][c0 + j] = expf(Sm[r][c0 + j] - mx);
        }
        __syncthreads();
        // ---- phase C: row sums, l update (32 threads)
        if (t < BQ) {
            float sum = 0.f;
            #pragma unroll
            for (int c = 0; c < BKV; ++c) sum += Sm[t][c];
            lrow[t] = lrow[t] * arow[t] + sum;
        }
        __syncthreads();
        // ---- rescale O, accumulate P @ V
        {
            float alpha = arow[r];
            #pragma unroll
            for (int i = 0; i < 16; ++i) o[i] *= alpha;
            #pragma unroll
            for (int k = 0; k < BKV; ++k) {
                float p = Sm[r][k];
                const float4* v4 = (const float4*)&Vs[k][d0];
                float4 v0 = v4[0], v1 = v4[1], v2 = v4[2], v3 = v4[3];
                o[0]  += p * v0.x; o[1]  += p * v0.y; o[2]  += p * v0.z; o[3]  += p * v0.w;
                o[4]  += p * v1.x; o[5]  += p * v1.y; o[6]  += p * v1.z; o[7]  += p * v1.w;
                o[8]  += p * v2.x; o[9]  += p * v2.y; o[10] += p * v2.z; o[11] += p * v2.w;
                o[12] += p * v3.x; o[13] += p * v3.y; o[14] += p * v3.z; o[15] += p * v3.w;
            }
        }
    }
    float linv = 1.0f / lrow[r];
    float* outp = y + ((size_t)(b * LL + q0 + r)) * EE + h * HD + d0;
    float4* out4 = (float4*)outp;
    float4 w0 = {o[0]*linv,  o[1]*linv,  o[2]*linv,  o[3]*linv};
    float4 w1 = {o[4]*linv,  o[5]*linv,  o[6]*linv,  o[7]*linv};
    float4 w2 = {o[8]*linv,  o[9]*linv,  o[10]*linv, o[11]*linv};
    float4 w3 = {o[12]*linv, o[13]*linv, o[14]*linv, o[15]*linv};
    out4[0] = w0; out4[1] = w1; out4[2] = w2; out4[3] = w3;
}

extern "C" void kernel_launch(void* const* d_in, const int* in_sizes, int n_in,
                              void* d_out, int out_size, void* d_ws, size_t ws_size,
                              hipStream_t stream) {
    const float* x      = (const float*)d_in[0];
    const int*   pos    = (const int*)d_in[1];
    const float* W_attn = (const float*)d_in[2];
    const float* b_attn = (const float*)d_in[3];
    const float* W_proj = (const float*)d_in[4];
    const float* b_proj = (const float*)d_in[5];
    float* out = (float*)d_out;

    float* qkv = (float*)d_ws;                       // B*L*3E floats (100.7 MB)
    float* y   = qkv + (size_t)BB * LL * N3E;        // B*L*E floats  (33.6 MB)

    dim3 blk(256);
    // 1) qkv = x @ W_attn + b_attn        [4096,2048]@[2048,6144]
    gemm_bias<<<dim3(N3E / 64, (BB * LL) / 64), blk, 0, stream>>>(
        x, W_attn, b_attn, qkv, BB * LL, N3E, EE);
    // 2) RoPE in place on q,k
    rope_kernel<<<dim3((BB * LL * HH * 64) / 256), blk, 0, stream>>>(qkv, pos);
    // 3) flash attention -> y in [B,L,E] layout
    flash_attn<<<dim3(LL / BQ, BB * HH), blk, 0, stream>>>(qkv, y);
    // 4) out = y @ W_proj + b_proj        [4096,2048]@[2048,2048]
    gemm_bias<<<dim3(EE / 64, (BB * LL) / 64), blk, 0, stream>>>(
        y, W_proj, b_proj, out, BB * LL, EE, EE);
}

// Round 2
// 2193.339 us; speedup vs baseline: 2.0952x; 2.0952x over previous
//
#include <hip/hip_runtime.h>
#include <math.h>

#define BB 2
#define LL 2048
#define EE 2048
#define HH 16
#define HD 128
#define N3E (3*EE)   // 6144

typedef __attribute__((ext_vector_type(8))) short  bf16x8;
typedef __attribute__((ext_vector_type(4))) float  f32x4;

__device__ __forceinline__ ushort f2bf(float f) {
    union { float f; unsigned u; } v; v.f = f;
    unsigned u = v.u + 0x7FFFu + ((v.u >> 16) & 1u);   // RNE
    return (ushort)(u >> 16);
}

// ---------------- GEMM: C = A @ W + bias (fp32, unchanged) ----------------
__global__ __launch_bounds__(256) void gemm_bias(const float* __restrict__ A,
                                                 const float* __restrict__ W,
                                                 const float* __restrict__ bias,
                                                 float* __restrict__ C,
                                                 int M, int N, int K) {
    __shared__ float As[16][68];
    __shared__ float Bs[16][64];
    const int t  = threadIdx.x;
    const int tx = t & 15, ty = t >> 4;
    const int n0 = blockIdx.x * 64;
    const int m0 = blockIdx.y * 64;
    float acc[4][4] = {};
    for (int k0 = 0; k0 < K; k0 += 16) {
        #pragma unroll
        for (int i = 0; i < 4; ++i) {
            int ii = t + i * 256;
            int m = ii >> 4, k = ii & 15;
            As[k][m] = A[(size_t)(m0 + m) * K + k0 + k];
        }
        #pragma unroll
        for (int i = 0; i < 4; ++i) {
            int ii = t + i * 256;
            int k = ii >> 6, n = ii & 63;
            Bs[k][n] = W[(size_t)(k0 + k) * N + n0 + n];
        }
        __syncthreads();
        #pragma unroll
        for (int k = 0; k < 16; ++k) {
            float4 a4 = *(const float4*)&As[k][ty * 4];
            float4 b4 = *(const float4*)&Bs[k][tx * 4];
            float av[4] = {a4.x, a4.y, a4.z, a4.w};
            float bv[4] = {b4.x, b4.y, b4.z, b4.w};
            #pragma unroll
            for (int i = 0; i < 4; ++i)
                #pragma unroll
                for (int j = 0; j < 4; ++j)
                    acc[i][j] += av[i] * bv[j];
        }
        __syncthreads();
    }
    #pragma unroll
    for (int i = 0; i < 4; ++i) {
        int m = m0 + ty * 4 + i;
        #pragma unroll
        for (int j = 0; j < 4; ++j) {
            int n = n0 + tx * 4 + j;
            C[(size_t)m * N + n] = acc[i][j] + bias[n];
        }
    }
}

// ---------------- RoPE (unchanged) ----------------
__global__ __launch_bounds__(256) void rope_kernel(float* __restrict__ qkv,
                                                   const int* __restrict__ pos_ids) {
    int idx = blockIdx.x * 256 + threadIdx.x;
    int j  = idx & 63;
    int h  = (idx >> 6) & 15;
    int bl = idx >> 10;
    float pos = (float)pos_ids[bl];
    float inv = powf(10000.0f, -(float)(2 * j) / 128.0f);
    float ang = pos * inv;
    float c = cosf(ang), s = sinf(ang);
    size_t base = (size_t)bl * N3E + h * HD;
    float x1 = qkv[base + j], x2 = qkv[base + j + 64];
    qkv[base + j]      = x1 * c - x2 * s;
    qkv[base + j + 64] = x2 * c + x1 * s;
    base += EE;
    x1 = qkv[base + j]; x2 = qkv[base + j + 64];
    qkv[base + j]      = x1 * c - x2 * s;
    qkv[base + j + 64] = x2 * c + x1 * s;
}

// ---------------- Flash attention, bf16 MFMA ----------------
// BQ=64 (4 waves x 16 q-rows), BKV=64 keys/tile, HD=128.
// mfma_f32_16x16x32_bf16 layouts (m89/m120-verified):
//   A-frag: A[m=lane&15][k=(lane>>4)*8+j]
//   B-frag: B[k=(lane>>4)*8+j][n=lane&15]   (== rows of B^T, gemm_bt pattern)
//   C/D   : col=lane&15, row=(lane>>4)*4+reg
#define BQ 64
#define BKV 64
#define QKSTR 136   // Qs/Ks row stride (ushorts): 128+8, 272B = 16B-aligned
#define VTSTR 72    // Vt/Ps row stride (ushorts): 64+8, 144B = 16B-aligned

__global__ __launch_bounds__(256) void flash_mfma(const float* __restrict__ qkv,
                                                  float* __restrict__ y) {
    // LDS: union(Qs[64][136], Vt[128][72]) | Ks[64][136] | Ps[4][16][72]
    __shared__ __align__(16) ushort smem[22528];   // 45056 B
    ushort* VtU = smem;                  // 9216 ushorts (also Qs: 8704)
    ushort* QsU = smem;
    ushort* KsU = smem + 9216;           // 8704 ushorts
    ushort* PsU = smem + 9216 + 8704;    // 4608 ushorts

    const int t    = threadIdx.x;
    const int w    = t >> 6;
    const int lane = t & 63;
    const int m    = lane & 15;
    const int quad = lane >> 4;
    const int q0   = blockIdx.x * BQ;
    const int bh   = blockIdx.y;
    const int b    = bh >> 4, h = bh & 15;
    const float scale = 0.08838834764831845f;   // 1/sqrt(128)

    const float* qbase = qkv + (size_t)b * LL * N3E + h * HD;
    const float* kbase = qbase + EE;
    const float* vbase = qbase + 2 * EE;

    // ---- stage Q tile -> LDS (bf16, row-major, stride QKSTR) ----
    #pragma unroll
    for (int i = 0; i < 8; ++i) {
        int idx = t + i * 256;            // 2048 float4s
        int r = idx >> 5, dg = idx & 31;
        float4 v = *(const float4*)(qbase + (size_t)(q0 + r) * N3E + dg * 4);
        ushort4 p = { f2bf(v.x), f2bf(v.y), f2bf(v.z), f2bf(v.w) };
        *(ushort4*)&QsU[r * QKSTR + dg * 4] = p;
    }
    __syncthreads();

    // ---- load Q A-frags into registers (held for whole kernel) ----
    bf16x8 qfrag[4];
    #pragma unroll
    for (int ks = 0; ks < 4; ++ks)
        qfrag[ks] = *(const bf16x8*)&QsU[(w * 16 + m) * QKSTR + ks * 32 + quad * 8];

    f32x4 oacc[8];
    #pragma unroll
    for (int dt = 0; dt < 8; ++dt) oacc[dt] = (f32x4){0.f, 0.f, 0.f, 0.f};
    float m_i[4], l_i[4];
    #pragma unroll
    for (int r = 0; r < 4; ++r) { m_i[r] = -INFINITY; l_i[r] = 0.f; }

    for (int kt = 0; kt < LL; kt += BKV) {
        __syncthreads();   // Q frags read (iter0) / prev-tile Ks,Vt reads done

        // ---- stage K tile (row-major bf16) ----
        #pragma unroll
        for (int i = 0; i < 8; ++i) {
            int idx = t + i * 256;
            int r = idx >> 5, dg = idx & 31;
            float4 v = *(const float4*)(kbase + (size_t)(kt + r) * N3E + dg * 4);
            ushort4 p = { f2bf(v.x), f2bf(v.y), f2bf(v.z), f2bf(v.w) };
            *(ushort4*)&KsU[r * QKSTR + dg * 4] = p;
        }
        // ---- stage V tile transposed: Vt[d][key] ----
        {
            int kb = (t >> 5) * 8;        // 0,8,...,56
            int dg = t & 31;              // d-group of 4
            float4 vv[8];
            #pragma unroll
            for (int j = 0; j < 8; ++j)
                vv[j] = *(const float4*)(vbase + (size_t)(kt + kb + j) * N3E + dg * 4);
            #pragma unroll
            for (int i = 0; i < 4; ++i) {
                bf16x8 pk;
                pk[0] = (short)f2bf(i == 0 ? vv[0].x : i == 1 ? vv[0].y : i == 2 ? vv[0].z : vv[0].w);
                pk[1] = (short)f2bf(i == 0 ? vv[1].x : i == 1 ? vv[1].y : i == 2 ? vv[1].z : vv[1].w);
                pk[2] = (short)f2bf(i == 0 ? vv[2].x : i == 1 ? vv[2].y : i == 2 ? vv[2].z : vv[2].w);
                pk[3] = (short)f2bf(i == 0 ? vv[3].x : i == 1 ? vv[3].y : i == 2 ? vv[3].z : vv[3].w);
                pk[4] = (short)f2bf(i == 0 ? vv[4].x : i == 1 ? vv[4].y : i == 2 ? vv[4].z : vv[4].w);
                pk[5] = (short)f2bf(i == 0 ? vv[5].x : i == 1 ? vv[5].y : i == 2 ? vv[5].z : vv[5].w);
                pk[6] = (short)f2bf(i == 0 ? vv[6].x : i == 1 ? vv[6].y : i == 2 ? vv[6].z : vv[6].w);
                pk[7] = (short)f2bf(i == 0 ? vv[7].x : i == 1 ? vv[7].y : i == 2 ? vv[7].z : vv[7].w);
                *(bf16x8*)&VtU[(dg * 4 + i) * VTSTR + kb] = pk;
            }
        }
        __syncthreads();

        // ---- S = Q @ K^T : 4 n-tiles x 4 k-steps ----
        f32x4 sacc[4];
        #pragma unroll
        for (int nt = 0; nt < 4; ++nt) sacc[nt] = (f32x4){0.f, 0.f, 0.f, 0.f};
        #pragma unroll
        for (int ks = 0; ks < 4; ++ks) {
            #pragma unroll
            for (int nt = 0; nt < 4; ++nt) {
                bf16x8 kf = *(const bf16x8*)&KsU[(nt * 16 + m) * QKSTR + ks * 32 + quad * 8];
                sacc[nt] = __builtin_amdgcn_mfma_f32_16x16x32_bf16(qfrag[ks], kf, sacc[nt], 0, 0, 0);
            }
        }

        // ---- online softmax (fp32, C-layout: row = quad*4+r, col = nt*16+m) ----
        float alpha[4];
        #pragma unroll
        for (int nt = 0; nt < 4; ++nt)
            #pragma unroll
            for (int r = 0; r < 4; ++r) sacc[nt][r] *= scale;
        #pragma unroll
        for (int r = 0; r < 4; ++r) {
            float mx = fmaxf(fmaxf(sacc[0][r], sacc[1][r]), fmaxf(sacc[2][r], sacc[3][r]));
            #pragma unroll
            for (int off = 1; off < 16; off <<= 1) mx = fmaxf(mx, __shfl_xor(mx, off, 64));
            float mnew = fmaxf(m_i[r], mx);
            alpha[r] = __expf(m_i[r] - mnew);
            m_i[r] = mnew;
            float rs = 0.f;
            #pragma unroll
            for (int nt = 0; nt < 4; ++nt) {
                float p = __expf(sacc[nt][r] - mnew);
                sacc[nt][r] = p;
                rs += p;
            }
            #pragma unroll
            for (int off = 1; off < 16; off <<= 1) rs += __shfl_xor(rs, off, 64);
            l_i[r] = l_i[r] * alpha[r] + rs;
        }
        #pragma unroll
        for (int dt = 0; dt < 8; ++dt)
            #pragma unroll
            for (int r = 0; r < 4; ++r) oacc[dt][r] *= alpha[r];

        // ---- P (bf16) -> LDS (C-layout -> A-layout round trip, wave-private) ----
        #pragma unroll
        for (int nt = 0; nt < 4; ++nt)
            #pragma unroll
            for (int r = 0; r < 4; ++r)
                PsU[w * 16 * VTSTR + (quad * 4 + r) * VTSTR + nt * 16 + m] = f2bf(sacc[nt][r]);

        // ---- O += P @ V ----
        #pragma unroll
        for (int ks2 = 0; ks2 < 2; ++ks2) {
            bf16x8 pf = *(const bf16x8*)&PsU[w * 16 * VTSTR + m * VTSTR + ks2 * 32 + quad * 8];
            #pragma unroll
            for (int dt = 0; dt < 8; ++dt) {
                bf16x8 vf = *(const bf16x8*)&VtU[(dt * 16 + m) * VTSTR + ks2 * 32 + quad * 8];
                oacc[dt] = __builtin_amdgcn_mfma_f32_16x16x32_bf16(pf, vf, oacc[dt], 0, 0, 0);
            }
        }
    }

    // ---- epilogue: normalize, write y[B,L,E] ----
    float linv[4];
    #pragma unroll
    for (int r = 0; r < 4; ++r) linv[r] = 1.f / l_i[r];
    #pragma unroll
    for (int dt = 0; dt < 8; ++dt) {
        #pragma unroll
        for (int r = 0; r < 4; ++r) {
            int row = q0 + w * 16 + quad * 4 + r;
            y[(size_t)(b * LL + row) * EE + h * HD + dt * 16 + m] = oacc[dt][r] * linv[r];
        }
    }
}

extern "C" void kernel_launch(void* const* d_in, const int* in_sizes, int n_in,
                              void* d_out, int out_size, void* d_ws, size_t ws_size,
                              hipStream_t stream) {
    const float* x      = (const float*)d_in[0];
    const int*   pos    = (const int*)d_in[1];
    const float* W_attn = (const float*)d_in[2];
    const float* b_attn = (const float*)d_in[3];
    const float* W_proj = (const float*)d_in[4];
    const float* b_proj = (const float*)d_in[5];
    float* out = (float*)d_out;

    float* qkv = (float*)d_ws;                       // B*L*3E floats
    float* y   = qkv + (size_t)BB * LL * N3E;        // B*L*E floats

    dim3 blk(256);
    gemm_bias<<<dim3(N3E / 64, (BB * LL) / 64), blk, 0, stream>>>(
        x, W_attn, b_attn, qkv, BB * LL, N3E, EE);
    rope_kernel<<<dim3((BB * LL * HH * 64) / 256), blk, 0, stream>>>(qkv, pos);
    flash_mfma<<<dim3(LL / BQ, BB * HH), blk, 0, stream>>>(qkv, y);
    gemm_bias<<<dim3(EE / 64, (BB * LL) / 64), blk, 0, stream>>>(
        y, W_proj, b_proj, out, BB * LL, EE, EE);
}

// Round 4
// 540.214 us; speedup vs baseline: 8.5067x; 4.0601x over previous
//
#include <hip/hip_runtime.h>
#include <math.h>

#define BB 2
#define LL 2048
#define EE 2048
#define HH 16
#define HD 128
#define N3E (3*EE)   // 6144

typedef __attribute__((ext_vector_type(8))) short  bf16x8;
typedef __attribute__((ext_vector_type(4))) float  f32x4;

__device__ __forceinline__ ushort f2bf(float f) {
    union { float f; unsigned u; } v; v.f = f;
    unsigned u = v.u + 0x7FFFu + ((v.u >> 16) & 1u);   // RNE
    return (ushort)(u >> 16);
}
__device__ __forceinline__ float bf2f(ushort u) {
    union { unsigned u; float f; } v; v.u = ((unsigned)u) << 16;
    return v.f;
}

// ---------------- fp32 -> bf16 convert (x) ----------------
__global__ __launch_bounds__(256) void cvt_bf16(const float* __restrict__ in,
                                                ushort* __restrict__ out, int n) {
    int i = (blockIdx.x * 256 + threadIdx.x) * 8;
    float4 a = *(const float4*)(in + i);
    float4 b = *(const float4*)(in + i + 4);
    ushort4 p0 = { f2bf(a.x), f2bf(a.y), f2bf(a.z), f2bf(a.w) };
    ushort4 p1 = { f2bf(b.x), f2bf(b.y), f2bf(b.z), f2bf(b.w) };
    *(ushort4*)(out + i)     = p0;
    *(ushort4*)(out + i + 4) = p1;
}

// ---------------- fp32 [R][C] -> bf16 [C][R] transpose (weights) ----------------
__global__ __launch_bounds__(256) void transpose_bf16(const float* __restrict__ in,
                                                      ushort* __restrict__ out,
                                                      int R, int Ccol) {
    __shared__ float tile[32][33];
    int c0 = blockIdx.x * 32, r0 = blockIdx.y * 32;
    int t = threadIdx.x;
    int lr = t >> 5, lc = t & 31;   // lr 0..7
    #pragma unroll
    for (int i = 0; i < 4; ++i)
        tile[lr + i * 8][lc] = in[(size_t)(r0 + lr + i * 8) * Ccol + c0 + lc];
    __syncthreads();
    #pragma unroll
    for (int i = 0; i < 4; ++i)
        out[(size_t)(c0 + lr + i * 8) * R + r0 + lc] = f2bf(tile[lc][lr + i * 8]);
}

// ---------------- bf16 MFMA GEMM: C = A @ Bt^T + bias (m97 structure) ----------------
// A [M][K] bf16, Bt [N][K] bf16, C [M][N] bf16 or fp32.
// 128x128 tile, BK=32, 256 threads (4 waves 2x2), 4x4 MFMA tiles/wave.
template<int WRITE_BF16>
__global__ __launch_bounds__(256) void gemm_bt_bf16(const ushort* __restrict__ A,
                                                    const ushort* __restrict__ Bt,
                                                    const float* __restrict__ bias,
                                                    void* __restrict__ C,
                                                    int M, int N, int K) {
    __shared__ __align__(16) ushort As[128 * 32];   // [row][k] stride 32, no pad (global_load_lds)
    __shared__ __align__(16) ushort Bs[128 * 32];
    const int t    = threadIdx.x;
    const int lane = t & 63, w = t >> 6;
    const int m    = lane & 15, quad = lane >> 4;
    const int wm   = w >> 1, wn = w & 1;
    const int m0   = blockIdx.y * 128, n0 = blockIdx.x * 128;

    f32x4 acc[4][4];
    #pragma unroll
    for (int i = 0; i < 4; ++i)
        #pragma unroll
        for (int j = 0; j < 4; ++j) acc[i][j] = (f32x4){0.f, 0.f, 0.f, 0.f};

    for (int k0 = 0; k0 < K; k0 += 32) {
        __syncthreads();
        #pragma unroll
        for (int i = 0; i < 2; ++i) {           // A tile: 512 x 16B chunks
            int c = t + i * 256;
            int row = c >> 2, kc = c & 3;
            __builtin_amdgcn_global_load_lds(
                (const __attribute__((address_space(1))) unsigned int*)(A + (size_t)(m0 + row) * K + k0 + kc * 8),
                (__attribute__((address_space(3))) unsigned int*)(As + c * 8),
                16, 0, 0);
        }
        #pragma unroll
        for (int i = 0; i < 2; ++i) {           // B tile
            int c = t + i * 256;
            int row = c >> 2, kc = c & 3;
            __builtin_amdgcn_global_load_lds(
                (const __attribute__((address_space(1))) unsigned int*)(Bt + (size_t)(n0 + row) * K + k0 + kc * 8),
                (__attribute__((address_space(3))) unsigned int*)(Bs + c * 8),
                16, 0, 0);
        }
        __syncthreads();
        bf16x8 af[4], bfr[4];
        #pragma unroll
        for (int mt = 0; mt < 4; ++mt)
            af[mt] = *(const bf16x8*)&As[(wm * 64 + mt * 16 + m) * 32 + quad * 8];
        #pragma unroll
        for (int nt = 0; nt < 4; ++nt)
            bfr[nt] = *(const bf16x8*)&Bs[(wn * 64 + nt * 16 + m) * 32 + quad * 8];
        #pragma unroll
        for (int mt = 0; mt < 4; ++mt)
            #pragma unroll
            for (int nt = 0; nt < 4; ++nt)
                acc[mt][nt] = __builtin_amdgcn_mfma_f32_16x16x32_bf16(af[mt], bfr[nt], acc[mt][nt], 0, 0, 0);
    }
    #pragma unroll
    for (int mt = 0; mt < 4; ++mt) {
        #pragma unroll
        for (int nt = 0; nt < 4; ++nt) {
            #pragma unroll
            for (int r = 0; r < 4; ++r) {
                int row = m0 + wm * 64 + mt * 16 + quad * 4 + r;
                int col = n0 + wn * 64 + nt * 16 + m;
                float v = acc[mt][nt][r] + bias[col];
                if (WRITE_BF16) ((ushort*)C)[(size_t)row * N + col] = f2bf(v);
                else            ((float*)C)[(size_t)row * N + col] = v;
            }
        }
    }
}

// ---------------- RoPE in-place on bf16 qkv; folds 1/sqrt(HD) into q ----------------
__global__ __launch_bounds__(256) void rope_bf16(ushort* __restrict__ qkv,
                                                 const int* __restrict__ pos_ids) {
    const float scale = 0.08838834764831845f;   // 1/sqrt(128)
    int idx = blockIdx.x * 256 + threadIdx.x;   // B*L*H*64 total
    int j  = idx & 63;
    int h  = (idx >> 6) & 15;
    int bl = idx >> 10;
    float pos = (float)pos_ids[bl];
    float inv = powf(10000.0f, -(float)(2 * j) / 128.0f);
    float ang = pos * inv;
    float s, c;
    sincosf(ang, &s, &c);
    size_t base = (size_t)bl * N3E + h * HD;
    float x1 = bf2f(qkv[base + j]), x2 = bf2f(qkv[base + j + 64]);
    qkv[base + j]      = f2bf((x1 * c - x2 * s) * scale);   // q: fold attn scale
    qkv[base + j + 64] = f2bf((x2 * c + x1 * s) * scale);
    base += EE;                                             // k: no scale
    x1 = bf2f(qkv[base + j]); x2 = bf2f(qkv[base + j + 64]);
    qkv[base + j]      = f2bf(x1 * c - x2 * s);
    qkv[base + j + 64] = f2bf(x2 * c + x1 * s);
}

// ---------------- Flash attention, bf16 MFMA (bf16 in/out) ----------------
#define BQ 64
#define BKV 64
#define QKSTR 136   // Qs/Ks row stride (ushorts)
#define VTSTR 72    // Vt/Ps row stride (ushorts)

__global__ __launch_bounds__(256) void flash_mfma(const ushort* __restrict__ qkv,
                                                  ushort* __restrict__ y) {
    __shared__ __align__(16) ushort smem[22528];   // 45056 B
    ushort* VtU = smem;                  // union with Qs
    ushort* QsU = smem;
    ushort* KsU = smem + 9216;
    ushort* PsU = smem + 9216 + 8704;

    const int t    = threadIdx.x;
    const int w    = t >> 6;
    const int lane = t & 63;
    const int m    = lane & 15;
    const int quad = lane >> 4;
    const int q0   = blockIdx.x * BQ;
    const int bh   = blockIdx.y;
    const int b    = bh >> 4, h = bh & 15;

    const ushort* qbase = qkv + (size_t)b * LL * N3E + h * HD;
    const ushort* kbase = qbase + EE;
    const ushort* vbase = qbase + 2 * EE;

    // ---- stage Q tile -> LDS (1024 x 16B chunks) ----
    #pragma unroll
    for (int i = 0; i < 4; ++i) {
        int idx = t + i * 256;
        int r = idx >> 4, cc = idx & 15;
        *(bf16x8*)&QsU[r * QKSTR + cc * 8] =
            *(const bf16x8*)(qbase + (size_t)(q0 + r) * N3E + cc * 8);
    }
    __syncthreads();

    bf16x8 qfrag[4];
    #pragma unroll
    for (int ks = 0; ks < 4; ++ks)
        qfrag[ks] = *(const bf16x8*)&QsU[(w * 16 + m) * QKSTR + ks * 32 + quad * 8];

    f32x4 oacc[8];
    #pragma unroll
    for (int dt = 0; dt < 8; ++dt) oacc[dt] = (f32x4){0.f, 0.f, 0.f, 0.f};
    float m_i[4], l_i[4];
    #pragma unroll
    for (int r = 0; r < 4; ++r) { m_i[r] = -INFINITY; l_i[r] = 0.f; }

    for (int kt = 0; kt < LL; kt += BKV) {
        __syncthreads();

        #pragma unroll
        for (int i = 0; i < 4; ++i) {       // K tile
            int idx = t + i * 256;
            int r = idx >> 4, cc = idx & 15;
            *(bf16x8*)&KsU[r * QKSTR + cc * 8] =
                *(const bf16x8*)(kbase + (size_t)(kt + r) * N3E + cc * 8);
        }
        {                                   // V tile transposed: Vt[d][key]
            int kb = (t >> 5) * 8;
            int dg = t & 31;
            ushort4 vv[8];
            #pragma unroll
            for (int j = 0; j < 8; ++j)
                vv[j] = *(const ushort4*)(vbase + (size_t)(kt + kb + j) * N3E + dg * 4);
            #pragma unroll
            for (int i = 0; i < 4; ++i) {
                bf16x8 pk;
                pk[0] = (short)(i == 0 ? vv[0].x : i == 1 ? vv[0].y : i == 2 ? vv[0].z : vv[0].w);
                pk[1] = (short)(i == 0 ? vv[1].x : i == 1 ? vv[1].y : i == 2 ? vv[1].z : vv[1].w);
                pk[2] = (short)(i == 0 ? vv[2].x : i == 1 ? vv[2].y : i == 2 ? vv[2].z : vv[2].w);
                pk[3] = (short)(i == 0 ? vv[3].x : i == 1 ? vv[3].y : i == 2 ? vv[3].z : vv[3].w);
                pk[4] = (short)(i == 0 ? vv[4].x : i == 1 ? vv[4].y : i == 2 ? vv[4].z : vv[4].w);
                pk[5] = (short)(i == 0 ? vv[5].x : i == 1 ? vv[5].y : i == 2 ? vv[5].z : vv[5].w);
                pk[6] = (short)(i == 0 ? vv[6].x : i == 1 ? vv[6].y : i == 2 ? vv[6].z : vv[6].w);
                pk[7] = (short)(i == 0 ? vv[7].x : i == 1 ? vv[7].y : i == 2 ? vv[7].z : vv[7].w);
                *(bf16x8*)&VtU[(dg * 4 + i) * VTSTR + kb] = pk;
            }
        }
        __syncthreads();

        // ---- S = Q @ K^T (scale pre-folded into q) ----
        f32x4 sacc[4];
        #pragma unroll
        for (int nt = 0; nt < 4; ++nt) sacc[nt] = (f32x4){0.f, 0.f, 0.f, 0.f};
        #pragma unroll
        for (int ks = 0; ks < 4; ++ks) {
            #pragma unroll
            for (int nt = 0; nt < 4; ++nt) {
                bf16x8 kf = *(const bf16x8*)&KsU[(nt * 16 + m) * QKSTR + ks * 32 + quad * 8];
                sacc[nt] = __builtin_amdgcn_mfma_f32_16x16x32_bf16(qfrag[ks], kf, sacc[nt], 0, 0, 0);
            }
        }

        // ---- online softmax ----
        float alpha[4];
        #pragma unroll
        for (int r = 0; r < 4; ++r) {
            float mx = fmaxf(fmaxf(sacc[0][r], sacc[1][r]), fmaxf(sacc[2][r], sacc[3][r]));
            #pragma unroll
            for (int off = 1; off < 16; off <<= 1) mx = fmaxf(mx, __shfl_xor(mx, off, 64));
            float mnew = fmaxf(m_i[r], mx);
            alpha[r] = __expf(m_i[r] - mnew);
            m_i[r] = mnew;
            float rs = 0.f;
            #pragma unroll
            for (int nt = 0; nt < 4; ++nt) {
                float p = __expf(sacc[nt][r] - mnew);
                sacc[nt][r] = p;
                rs += p;
            }
            #pragma unroll
            for (int off = 1; off < 16; off <<= 1) rs += __shfl_xor(rs, off, 64);
            l_i[r] = l_i[r] * alpha[r] + rs;
        }
        #pragma unroll
        for (int dt = 0; dt < 8; ++dt)
            #pragma unroll
            for (int r = 0; r < 4; ++r) oacc[dt][r] *= alpha[r];

        // ---- P -> LDS (C-layout -> A-layout) ----
        #pragma unroll
        for (int nt = 0; nt < 4; ++nt)
            #pragma unroll
            for (int r = 0; r < 4; ++r)
                PsU[w * 16 * VTSTR + (quad * 4 + r) * VTSTR + nt * 16 + m] = f2bf(sacc[nt][r]);

        // ---- O += P @ V ----
        #pragma unroll
        for (int ks2 = 0; ks2 < 2; ++ks2) {
            bf16x8 pf = *(const bf16x8*)&PsU[w * 16 * VTSTR + m * VTSTR + ks2 * 32 + quad * 8];
            #pragma unroll
            for (int dt = 0; dt < 8; ++dt) {
                bf16x8 vf = *(const bf16x8*)&VtU[(dt * 16 + m) * VTSTR + ks2 * 32 + quad * 8];
                oacc[dt] = __builtin_amdgcn_mfma_f32_16x16x32_bf16(pf, vf, oacc[dt], 0, 0, 0);
            }
        }
    }

    float linv[4];
    #pragma unroll
    for (int r = 0; r < 4; ++r) linv[r] = 1.f / l_i[r];
    #pragma unroll
    for (int dt = 0; dt < 8; ++dt) {
        #pragma unroll
        for (int r = 0; r < 4; ++r) {
            int row = q0 + w * 16 + quad * 4 + r;
            y[(size_t)(b * LL + row) * EE + h * HD + dt * 16 + m] = f2bf(oacc[dt][r] * linv[r]);
        }
    }
}

extern "C" void kernel_launch(void* const* d_in, const int* in_sizes, int n_in,
                              void* d_out, int out_size, void* d_ws, size_t ws_size,
                              hipStream_t stream) {
    const float* x      = (const float*)d_in[0];
    const int*   pos    = (const int*)d_in[1];
    const float* W_attn = (const float*)d_in[2];
    const float* b_attn = (const float*)d_in[3];
    const float* W_proj = (const float*)d_in[4];
    const float* b_proj = (const float*)d_in[5];
    float* out = (float*)d_out;

    // workspace layout (ushorts)
    ushort* xb   = (ushort*)d_ws;                        //  16.8 MB  [M][K]
    ushort* Wat  = xb   + (size_t)BB * LL * EE;          //  25.2 MB  [3E][E]
    ushort* Wpt  = Wat  + (size_t)N3E * EE;              //   8.4 MB  [E][E]
    ushort* qkvb = Wpt  + (size_t)EE * EE;               //  50.3 MB  [B*L][3E]
    ushort* yb   = qkvb + (size_t)BB * LL * N3E;         //  16.8 MB  [B*L][E]

    dim3 blk(256);
    const int M = BB * LL;   // 4096

    cvt_bf16<<<dim3(M * EE / (256 * 8)), blk, 0, stream>>>(x, xb, M * EE);
    transpose_bf16<<<dim3(N3E / 32, EE / 32), blk, 0, stream>>>(W_attn, Wat, EE, N3E);
    transpose_bf16<<<dim3(EE / 32, EE / 32), blk, 0, stream>>>(W_proj, Wpt, EE, EE);

    gemm_bt_bf16<1><<<dim3(N3E / 128, M / 128), blk, 0, stream>>>(
        xb, Wat, b_attn, qkvb, M, N3E, EE);
    rope_bf16<<<dim3((BB * LL * HH * 64) / 256), blk, 0, stream>>>(qkvb, pos);
    flash_mfma<<<dim3(LL / BQ, BB * HH), blk, 0, stream>>>(qkvb, yb);
    gemm_bt_bf16<0><<<dim3(EE / 128, M / 128), blk, 0, stream>>>(
        yb, Wpt, b_proj, out, M, EE, EE);
}

// Round 5
// 508.530 us; speedup vs baseline: 9.0367x; 1.0623x over previous
//
#include <hip/hip_runtime.h>
#include <math.h>

#define BB 2
#define LL 2048
#define EE 2048
#define HH 16
#define HD 128
#define N3E (3*EE)   // 6144

typedef __attribute__((ext_vector_type(8))) short  bf16x8;
typedef __attribute__((ext_vector_type(4))) float  f32x4;

__device__ __forceinline__ ushort f2bf(float f) {
    union { float f; unsigned u; } v; v.f = f;
    unsigned u = v.u + 0x7FFFu + ((v.u >> 16) & 1u);   // RNE
    return (ushort)(u >> 16);
}
__device__ __forceinline__ float bf2f(ushort u) {
    union { unsigned u; float f; } v; v.u = ((unsigned)u) << 16;
    return v.f;
}

// ---------------- fp32 -> bf16 convert (x) ----------------
__global__ __launch_bounds__(256) void cvt_bf16(const float* __restrict__ in,
                                                ushort* __restrict__ out, int n) {
    int i = (blockIdx.x * 256 + threadIdx.x) * 8;
    float4 a = *(const float4*)(in + i);
    float4 b = *(const float4*)(in + i + 4);
    ushort4 p0 = { f2bf(a.x), f2bf(a.y), f2bf(a.z), f2bf(a.w) };
    ushort4 p1 = { f2bf(b.x), f2bf(b.y), f2bf(b.z), f2bf(b.w) };
    *(ushort4*)(out + i)     = p0;
    *(ushort4*)(out + i + 4) = p1;
}

// ---------------- fp32 [R][C] -> bf16 [C][R] transpose (weights) ----------------
__global__ __launch_bounds__(256) void transpose_bf16(const float* __restrict__ in,
                                                      ushort* __restrict__ out,
                                                      int R, int Ccol) {
    __shared__ float tile[32][33];
    int c0 = blockIdx.x * 32, r0 = blockIdx.y * 32;
    int t = threadIdx.x;
    int lr = t >> 5, lc = t & 31;
    #pragma unroll
    for (int i = 0; i < 4; ++i)
        tile[lr + i * 8][lc] = in[(size_t)(r0 + lr + i * 8) * Ccol + c0 + lc];
    __syncthreads();
    #pragma unroll
    for (int i = 0; i < 4; ++i)
        out[(size_t)(c0 + lr + i * 8) * R + r0 + lc] = f2bf(tile[lc][lr + i * 8]);
}

// ---------------- bf16 MFMA GEMM (m97 structure, unchanged) ----------------
template<int WRITE_BF16>
__global__ __launch_bounds__(256) void gemm_bt_bf16(const ushort* __restrict__ A,
                                                    const ushort* __restrict__ Bt,
                                                    const float* __restrict__ bias,
                                                    void* __restrict__ C,
                                                    int M, int N, int K) {
    __shared__ __align__(16) ushort As[128 * 32];
    __shared__ __align__(16) ushort Bs[128 * 32];
    const int t    = threadIdx.x;
    const int lane = t & 63, w = t >> 6;
    const int m    = lane & 15, quad = lane >> 4;
    const int wm   = w >> 1, wn = w & 1;
    const int m0   = blockIdx.y * 128, n0 = blockIdx.x * 128;

    f32x4 acc[4][4];
    #pragma unroll
    for (int i = 0; i < 4; ++i)
        #pragma unroll
        for (int j = 0; j < 4; ++j) acc[i][j] = (f32x4){0.f, 0.f, 0.f, 0.f};

    for (int k0 = 0; k0 < K; k0 += 32) {
        __syncthreads();
        #pragma unroll
        for (int i = 0; i < 2; ++i) {
            int c = t + i * 256;
            int row = c >> 2, kc = c & 3;
            __builtin_amdgcn_global_load_lds(
                (const __attribute__((address_space(1))) unsigned int*)(A + (size_t)(m0 + row) * K + k0 + kc * 8),
                (__attribute__((address_space(3))) unsigned int*)(As + c * 8),
                16, 0, 0);
        }
        #pragma unroll
        for (int i = 0; i < 2; ++i) {
            int c = t + i * 256;
            int row = c >> 2, kc = c & 3;
            __builtin_amdgcn_global_load_lds(
                (const __attribute__((address_space(1))) unsigned int*)(Bt + (size_t)(n0 + row) * K + k0 + kc * 8),
                (__attribute__((address_space(3))) unsigned int*)(Bs + c * 8),
                16, 0, 0);
        }
        __syncthreads();
        bf16x8 af[4], bfr[4];
        #pragma unroll
        for (int mt = 0; mt < 4; ++mt)
            af[mt] = *(const bf16x8*)&As[(wm * 64 + mt * 16 + m) * 32 + quad * 8];
        #pragma unroll
        for (int nt = 0; nt < 4; ++nt)
            bfr[nt] = *(const bf16x8*)&Bs[(wn * 64 + nt * 16 + m) * 32 + quad * 8];
        #pragma unroll
        for (int mt = 0; mt < 4; ++mt)
            #pragma unroll
            for (int nt = 0; nt < 4; ++nt)
                acc[mt][nt] = __builtin_amdgcn_mfma_f32_16x16x32_bf16(af[mt], bfr[nt], acc[mt][nt], 0, 0, 0);
    }
    #pragma unroll
    for (int mt = 0; mt < 4; ++mt) {
        #pragma unroll
        for (int nt = 0; nt < 4; ++nt) {
            #pragma unroll
            for (int r = 0; r < 4; ++r) {
                int row = m0 + wm * 64 + mt * 16 + quad * 4 + r;
                int col = n0 + wn * 64 + nt * 16 + m;
                float v = acc[mt][nt][r] + bias[col];
                if (WRITE_BF16) ((ushort*)C)[(size_t)row * N + col] = f2bf(v);
                else            ((float*)C)[(size_t)row * N + col] = v;
            }
        }
    }
}

// ---------------- prep: RoPE + scale + tile/swizzle Q,K ----------------
// Output tiles per (b,h): 32 tiles x [64 rows][16 chunks of 16B], chunk stored
// at physical p holds logical chunk c = p ^ (r&15).  Q gets 1/sqrt(HD) folded.
__global__ __launch_bounds__(256) void prep_qk(const ushort* __restrict__ qkvb,
                                               const int* __restrict__ pos_ids,
                                               ushort* __restrict__ Qt,
                                               ushort* __restrict__ Kt) {
    const float scale = 0.08838834764831845f;
    int idx = blockIdx.x * 256 + threadIdx.x;      // B*H*32*64*16 = 1048576
    int p    = idx & 15;
    int r    = (idx >> 4) & 63;
    int tile = (idx >> 10) & 31;
    int h    = (idx >> 15) & 15;
    int b    = idx >> 19;
    int c    = p ^ (r & 15);
    int l    = tile * 64 + r;
    int half = c >> 3, cl = c & 7;
    const ushort* row = qkvb + (size_t)(b * LL + l) * N3E;
    float pos = (float)pos_ids[b * LL + l];

    bf16x8 qa = *(const bf16x8*)(row + h * HD + c * 8);
    bf16x8 qb = *(const bf16x8*)(row + h * HD + (c ^ 8) * 8);
    bf16x8 ka = *(const bf16x8*)(row + EE + h * HD + c * 8);
    bf16x8 kb = *(const bf16x8*)(row + EE + h * HD + (c ^ 8) * 8);
    bf16x8 qo, ko;
    #pragma unroll
    for (int i = 0; i < 8; ++i) {
        int j = cl * 8 + i;
        float ang = pos * powf(10000.0f, -(float)j / 64.0f);
        float s, cs;
        sincosf(ang, &s, &cs);
        float sgn = half ? s : -s;
        float q1 = bf2f((ushort)qa[i]), q2 = bf2f((ushort)qb[i]);
        float k1 = bf2f((ushort)ka[i]), k2 = bf2f((ushort)kb[i]);
        qo[i] = (short)f2bf((q1 * cs + q2 * sgn) * scale);
        ko[i] = (short)f2bf(k1 * cs + k2 * sgn);
    }
    size_t obase = ((size_t)(b * 16 + h) * 32 + tile) * 8192 + r * 128 + p * 8;
    *(bf16x8*)(Qt + obase) = qo;
    *(bf16x8*)(Kt + obase) = ko;
}

// ---------------- prep: V -> V^T tiles ----------------
// Per (b,h): 32 tiles x [128 rows (d)][8 chunks], physical p holds c = p^(r&7).
__global__ __launch_bounds__(256) void prep_v(const ushort* __restrict__ qkvb,
                                              ushort* __restrict__ Vtt) {
    int idx = blockIdx.x * 256 + threadIdx.x;      // B*H*32*128*8 = 1048576
    int p    = idx & 7;
    int r    = (idx >> 3) & 127;                    // d
    int tile = (idx >> 10) & 31;
    int h    = (idx >> 15) & 15;
    int b    = idx >> 19;
    int c    = p ^ (r & 7);
    int col  = 2 * EE + h * HD + r;
    bf16x8 o;
    #pragma unroll
    for (int i = 0; i < 8; ++i) {
        int kk = tile * 64 + c * 8 + i;
        o[i] = (short)qkvb[(size_t)(b * LL + kk) * N3E + col];
    }
    *(bf16x8*)(Vtt + ((size_t)(b * 16 + h) * 32 + tile) * 8192 + r * 64 + p * 8) = o;
}

// ---------------- Flash attention v2: BQ=128, global_load_lds staging ----------------
#define PSTR 68

__global__ __launch_bounds__(256, 2) void flash2(const ushort* __restrict__ Qt,
                                                 const ushort* __restrict__ Kt,
                                                 const ushort* __restrict__ Vtt,
                                                 ushort* __restrict__ y) {
    __shared__ __align__(16) ushort Ks[64 * 128];    // 16 KB, swizzled tile image
    __shared__ __align__(16) ushort Vs[128 * 64];    // 16 KB
    __shared__ __align__(16) ushort Ps[4 * 32 * PSTR];

    const int t    = threadIdx.x;
    const int w    = t >> 6;
    const int lane = t & 63;
    const int m    = lane & 15;
    const int quad = lane >> 4;
    const int qblk = blockIdx.x;                     // 0..15
    const int bh   = blockIdx.y;
    const int b    = bh >> 4, h = bh & 15;

    const ushort* Qhead = Qt  + (size_t)bh * 32 * 8192;
    const ushort* Khead = Kt  + (size_t)bh * 32 * 8192;
    const ushort* Vhead = Vtt + (size_t)bh * 32 * 8192;

    // ---- Q A-frags direct from global (one-time) ----
    bf16x8 qf[2][4];
    #pragma unroll
    for (int mt = 0; mt < 2; ++mt) {
        int rloc = w * 32 + mt * 16 + m;             // 0..127; rloc&15 == m
        const ushort* qtile = Qhead + (size_t)(qblk * 2 + (rloc >> 6)) * 8192
                              + (rloc & 63) * 128;
        #pragma unroll
        for (int ks = 0; ks < 4; ++ks)
            qf[mt][ks] = *(const bf16x8*)(qtile + ((ks * 4 + quad) ^ m) * 8);
    }

    f32x4 oacc[2][8];
    #pragma unroll
    for (int mt = 0; mt < 2; ++mt)
        #pragma unroll
        for (int dt = 0; dt < 8; ++dt) oacc[mt][dt] = (f32x4){0.f, 0.f, 0.f, 0.f};
    float m_i[8], l_pl[8];
    #pragma unroll
    for (int s = 0; s < 8; ++s) { m_i[s] = -INFINITY; l_pl[s] = 0.f; }

    for (int kt = 0; kt < 32; ++kt) {
        __syncthreads();                             // prev-tile reads done
        const ushort* ksrc = Khead + (size_t)kt * 8192;
        const ushort* vsrc = Vhead + (size_t)kt * 8192;
        #pragma unroll
        for (int i = 0; i < 4; ++i) {
            int cid = t + i * 256;
            __builtin_amdgcn_global_load_lds(
                (const __attribute__((address_space(1))) unsigned int*)(ksrc + cid * 8),
                (__attribute__((address_space(3))) unsigned int*)(Ks + cid * 8),
                16, 0, 0);
        }
        #pragma unroll
        for (int i = 0; i < 4; ++i) {
            int cid = t + i * 256;
            __builtin_amdgcn_global_load_lds(
                (const __attribute__((address_space(1))) unsigned int*)(vsrc + cid * 8),
                (__attribute__((address_space(3))) unsigned int*)(Vs + cid * 8),
                16, 0, 0);
        }
        __syncthreads();                             // vmcnt(0) drain + barrier

        // ---- S = Q @ K^T : 32 MFMA from 16 K-frag reads ----
        f32x4 sacc[2][4];
        #pragma unroll
        for (int mt = 0; mt < 2; ++mt)
            #pragma unroll
            for (int nt = 0; nt < 4; ++nt) sacc[mt][nt] = (f32x4){0.f, 0.f, 0.f, 0.f};
        #pragma unroll
        for (int ks = 0; ks < 4; ++ks) {
            #pragma unroll
            for (int nt = 0; nt < 4; ++nt) {
                bf16x8 kf = *(const bf16x8*)&Ks[(nt * 16 + m) * 128 + (((ks * 4 + quad) ^ m)) * 8];
                sacc[0][nt] = __builtin_amdgcn_mfma_f32_16x16x32_bf16(qf[0][ks], kf, sacc[0][nt], 0, 0, 0);
                sacc[1][nt] = __builtin_amdgcn_mfma_f32_16x16x32_bf16(qf[1][ks], kf, sacc[1][nt], 0, 0, 0);
            }
        }

        // ---- online softmax (deferred l cross-lane reduction) ----
        float alpha_s[2][4];
        #pragma unroll
        for (int mt = 0; mt < 2; ++mt) {
            #pragma unroll
            for (int r = 0; r < 4; ++r) {
                int slot = mt * 4 + r;
                float mx = fmaxf(fmaxf(sacc[mt][0][r], sacc[mt][1][r]),
                                 fmaxf(sacc[mt][2][r], sacc[mt][3][r]));
                #pragma unroll
                for (int off = 1; off < 16; off <<= 1) mx = fmaxf(mx, __shfl_xor(mx, off, 64));
                float mnew = fmaxf(m_i[slot], mx);
                float al = __expf(m_i[slot] - mnew);
                m_i[slot] = mnew;
                float rs = 0.f;
                #pragma unroll
                for (int nt = 0; nt < 4; ++nt) {
                    float pv = __expf(sacc[mt][nt][r] - mnew);
                    sacc[mt][nt][r] = pv;
                    rs += pv;
                }
                l_pl[slot] = l_pl[slot] * al + rs;     // lane-partial row sum
                alpha_s[mt][r] = al;
            }
        }
        #pragma unroll
        for (int mt = 0; mt < 2; ++mt)
            #pragma unroll
            for (int dt = 0; dt < 8; ++dt)
                #pragma unroll
                for (int r = 0; r < 4; ++r) oacc[mt][dt][r] *= alpha_s[mt][r];

        // ---- P -> LDS (wave-private; C-layout -> A-layout) ----
        #pragma unroll
        for (int mt = 0; mt < 2; ++mt)
            #pragma unroll
            for (int nt = 0; nt < 4; ++nt)
                #pragma unroll
                for (int r = 0; r < 4; ++r)
                    Ps[w * 32 * PSTR + (mt * 16 + quad * 4 + r) * PSTR + nt * 16 + m]
                        = f2bf(sacc[mt][nt][r]);

        // ---- O += P @ V : 32 MFMA from 16 V-frag + 4 P-frag reads ----
        #pragma unroll
        for (int ks2 = 0; ks2 < 2; ++ks2) {
            bf16x8 pf0 = *(const bf16x8*)&Ps[w * 32 * PSTR + (0 * 16 + m) * PSTR + ks2 * 32 + quad * 8];
            bf16x8 pf1 = *(const bf16x8*)&Ps[w * 32 * PSTR + (1 * 16 + m) * PSTR + ks2 * 32 + quad * 8];
            #pragma unroll
            for (int dt = 0; dt < 8; ++dt) {
                bf16x8 vf = *(const bf16x8*)&Vs[(dt * 16 + m) * 64 + (((ks2 * 4 + quad) ^ (m & 7))) * 8];
                oacc[0][dt] = __builtin_amdgcn_mfma_f32_16x16x32_bf16(pf0, vf, oacc[0][dt], 0, 0, 0);
                oacc[1][dt] = __builtin_amdgcn_mfma_f32_16x16x32_bf16(pf1, vf, oacc[1][dt], 0, 0, 0);
            }
        }
    }

    // ---- epilogue: finish l reduction, normalize, write ----
    #pragma unroll
    for (int s = 0; s < 8; ++s) {
        #pragma unroll
        for (int off = 1; off < 16; off <<= 1) l_pl[s] += __shfl_xor(l_pl[s], off, 64);
        l_pl[s] = 1.0f / l_pl[s];
    }
    #pragma unroll
    for (int mt = 0; mt < 2; ++mt) {
        #pragma unroll
        for (int dt = 0; dt < 8; ++dt) {
            #pragma unroll
            for (int r = 0; r < 4; ++r) {
                int row = qblk * 128 + w * 32 + mt * 16 + quad * 4 + r;
                y[(size_t)(b * LL + row) * EE + h * HD + dt * 16 + m]
                    = f2bf(oacc[mt][dt][r] * l_pl[mt * 4 + r]);
            }
        }
    }
}

extern "C" void kernel_launch(void* const* d_in, const int* in_sizes, int n_in,
                              void* d_out, int out_size, void* d_ws, size_t ws_size,
                              hipStream_t stream) {
    const float* x      = (const float*)d_in[0];
    const int*   pos    = (const int*)d_in[1];
    const float* W_attn = (const float*)d_in[2];
    const float* b_attn = (const float*)d_in[3];
    const float* W_proj = (const float*)d_in[4];
    const float* b_proj = (const float*)d_in[5];
    float* out = (float*)d_out;

    const int M = BB * LL;   // 4096
    // workspace (ushorts), 134.2 MB total with aliasing:
    ushort* xb   = (ushort*)d_ws;                    // [M][E]      16.8 MB  (→ Qt after gemm1)
    ushort* Wat  = xb   + (size_t)M * EE;            // [3E][E]     25.2 MB  (→ yb after prep)
    ushort* Wpt  = Wat  + (size_t)N3E * EE;          // [E][E]       8.4 MB
    ushort* qkvb = Wpt  + (size_t)EE * EE;           // [M][3E]     50.3 MB
    ushort* Kt   = qkvb + (size_t)M * N3E;           // tiles       16.8 MB
    ushort* Vtt  = Kt   + (size_t)M * EE;            // tiles       16.8 MB
    ushort* Qt   = xb;                               // alias (xb dead after gemm1)
    ushort* yb   = Wat;                              // alias (Wat dead after gemm1)

    dim3 blk(256);
    cvt_bf16<<<dim3(M * EE / (256 * 8)), blk, 0, stream>>>(x, xb, M * EE);
    transpose_bf16<<<dim3(N3E / 32, EE / 32), blk, 0, stream>>>(W_attn, Wat, EE, N3E);
    transpose_bf16<<<dim3(EE / 32, EE / 32), blk, 0, stream>>>(W_proj, Wpt, EE, EE);

    gemm_bt_bf16<1><<<dim3(N3E / 128, M / 128), blk, 0, stream>>>(
        xb, Wat, b_attn, qkvb, M, N3E, EE);

    prep_qk<<<dim3(4096), blk, 0, stream>>>(qkvb, pos, Qt, Kt);
    prep_v<<<dim3(4096), blk, 0, stream>>>(qkvb, Vtt);

    flash2<<<dim3(LL / 128, BB * HH), blk, 0, stream>>>(Qt, Kt, Vtt, yb);

    gemm_bt_bf16<0><<<dim3(EE / 128, M / 128), blk, 0, stream>>>(
        yb, Wpt, b_proj, out, M, EE, EE);
}